// Round 6
// baseline (364.125 us; speedup 1.0000x reference)
//
#include <hip/hip_runtime.h>
#include <math.h>

// Problem shapes
constexpr int B = 4, H = 16, S = 1024, D = 256, P = 64;
constexpr long long N_ROWS = (long long)B * H * S;            // 65536
// Output segment offsets (floats, concatenated in return order)
constexpr long long OFF_RT = 0;                               // routing_scores
constexpr long long SZ_RT  = N_ROWS;                          // 65536
constexpr long long OFF_OR = OFF_RT + SZ_RT;                  // optimal_routes
constexpr long long SZ_OR  = N_ROWS * (long long)S;           // 67108864
constexpr long long OFF_TW = OFF_OR + SZ_OR;                  // transfer_weights
constexpr long long SZ_TW  = 16LL * 64 * 64;                  // 65536
constexpr long long OFF_PS = OFF_TW + SZ_TW;                  // pattern_scores

typedef _Float16 half8   __attribute__((ext_vector_type(8)));
typedef _Float16 half4v  __attribute__((ext_vector_type(4)));
typedef float    floatx4 __attribute__((ext_vector_type(4)));   // clang vector:
// legal for __builtin_nontemporal_* (HIP's float4 struct is not)

// ---------------------------------------------------------------------------
// Kernel 1: normalize patterns, fold in 1/TEMPERATURE = 10, split into f16
// hi/lo (a = hi + lo) for split-precision MFMA. Layout [p][k] row-major.
__global__ __launch_bounds__(64) void k_normalize(const float* __restrict__ pat,
                                                  _Float16* __restrict__ pnh,
                                                  _Float16* __restrict__ pnl) {
    int p    = blockIdx.x;
    int lane = threadIdx.x;                 // 0..63, covers 256 floats as floatx4
    const floatx4* src = (const floatx4*)(pat + (long long)p * D);
    floatx4 v = src[lane];
    float ss = v.x * v.x + v.y * v.y + v.z * v.z + v.w * v.w;
    #pragma unroll
    for (int m = 1; m < 64; m <<= 1) ss += __shfl_xor(ss, m, 64);
    float scale = 10.0f / fmaxf(sqrtf(ss), 1e-12f);
    float a[4] = { v.x * scale, v.y * scale, v.z * scale, v.w * scale };
    half4v hh, ll;
    #pragma unroll
    for (int j = 0; j < 4; ++j) {
        _Float16 h = (_Float16)a[j];
        hh[j] = h;
        ll[j] = (_Float16)(a[j] - (float)h);
    }
    *(half4v*)(pnh + (long long)p * D + lane * 4) = hh;
    *(half4v*)(pnl + (long long)p * D + lane * 4) = ll;
}

// ---------------------------------------------------------------------------
// Kernel 2: routing_scores = 1/1024 (constant) + transfer_weights copy,
// float4-vectorized. 128 blocks x 256 threads x float4 = 2 x 65536 floats.
__global__ __launch_bounds__(256) void k_small(const floatx4* __restrict__ tw,
                                               float* __restrict__ out) {
    int i = blockIdx.x * 256 + threadIdx.x;          // 0..32767
    constexpr int Q = (int)SZ_RT / 4;                // 16384 float4 per segment
    if (i < Q) {
        floatx4 v = { 0.0009765625f, 0.0009765625f, 0.0009765625f, 0.0009765625f };
        ((floatx4*)(out + OFF_RT))[i] = v;
    } else {
        ((floatx4*)(out + OFF_TW))[i - Q] = tw[i - Q];
    }
}

// ---------------------------------------------------------------------------
// Kernel 3: optimal_routes[..., j] = -j/1024. 256 MB pure store stream.
// Grid-stride (4096 blocks, 16 stores/thread): stride 2^20 float4s is
// 0 mod 1024 -> each thread's column block (and value v) is iteration-
// invariant. Non-temporal: pure streaming writes, keep them out of L2.
// R4 lesson: do NOT mix this write stream with the gemm's read stream in
// one kernel (HBM read/write turnaround cost ~15 us); serialized pure
// streams are faster.
__global__ __launch_bounds__(256) void k_routes(floatx4* __restrict__ out) {
    long long tid = (long long)blockIdx.x * 256 + threadIdx.x;   // 0..2^20-1
    int j0 = (int)((tid << 2) & (S - 1));            // float4-aligned column
    float b0 = (float)j0 * (-0.0009765625f);
    floatx4 v;
    v.x = b0;
    v.y = b0 - 0.0009765625f;
    v.z = b0 - 0.001953125f;
    v.w = b0 - 0.0029296875f;
    floatx4* dst = out + tid;
    #pragma unroll
    for (int i = 0; i < 16; ++i) {
        __builtin_nontemporal_store(v, dst + (long long)i * (1 << 20));
    }
}

// ---------------------------------------------------------------------------
// Kernel 4: sims = states @ pn^T via f16 split-precision MFMA, then row
// softmax over 64 patterns. (Byte-identical structure to R2's 25 us kernel.)
//   Block = 256 thr = 4 waves; block tile = 64 rows; wave tile = 16 rows x 64.
//   A-frags converted fp32->f16 hi/lo in-register (Ootomo 3-product scheme).
//   C/D layout: col = lane&15, row = (lane>>4)*4 + reg (guide §3, measured).
__global__ __launch_bounds__(256) void k_gemm_mfma(
        const float* __restrict__ states,
        const _Float16* __restrict__ pnh,
        const _Float16* __restrict__ pnl,
        float* __restrict__ out_ps) {
    int wave = threadIdx.x >> 6;
    int lane = threadIdx.x & 63;
    int q    = lane >> 4;                  // quad 0..3
    int m    = lane & 15;
    long long row0 = (long long)blockIdx.x * 64 + wave * 16;
    const float* __restrict__ arow = states + (row0 + m) * D + q * 8;

    floatx4 acc[4] = {floatx4{0,0,0,0}, floatx4{0,0,0,0},
                      floatx4{0,0,0,0}, floatx4{0,0,0,0}};

    #pragma unroll 2
    for (int kk = 0; kk < 8; ++kk) {
        float4 a0 = *(const float4*)(arow + kk * 32);
        float4 a1 = *(const float4*)(arow + kk * 32 + 4);
        float av[8] = { a0.x, a0.y, a0.z, a0.w, a1.x, a1.y, a1.z, a1.w };
        half8 ah, al;
        #pragma unroll
        for (int j = 0; j < 8; ++j) {
            _Float16 h = (_Float16)av[j];
            ah[j] = h;
            al[j] = (_Float16)(av[j] - (float)h);
        }
        #pragma unroll
        for (int t = 0; t < 4; ++t) {
            long long boff = (long long)(t * 16 + m) * D + kk * 32 + q * 8;
            half8 bh = *(const half8*)(pnh + boff);
            half8 bl = *(const half8*)(pnl + boff);
            acc[t] = __builtin_amdgcn_mfma_f32_16x16x32_f16(ah, bh, acc[t], 0, 0, 0);
            acc[t] = __builtin_amdgcn_mfma_f32_16x16x32_f16(al, bh, acc[t], 0, 0, 0);
            acc[t] = __builtin_amdgcn_mfma_f32_16x16x32_f16(ah, bl, acc[t], 0, 0, 0);
        }
    }

    // Row softmax: row = q*4 + r lives in the 16 lanes sharing q (shuffle
    // masks 1..8 stay inside the group); each lane holds 4 cols (one per tile).
    float e[4][4];
    #pragma unroll
    for (int r = 0; r < 4; ++r) {
        float mx = fmaxf(fmaxf(acc[0][r], acc[1][r]), fmaxf(acc[2][r], acc[3][r]));
        #pragma unroll
        for (int msk = 1; msk < 16; msk <<= 1) mx = fmaxf(mx, __shfl_xor(mx, msk, 64));
        float s = 0.0f;
        #pragma unroll
        for (int t = 0; t < 4; ++t) { e[t][r] = __expf(acc[t][r] - mx); s += e[t][r]; }
        #pragma unroll
        for (int msk = 1; msk < 16; msk <<= 1) s += __shfl_xor(s, msk, 64);
        float inv = 1.0f / s;
        long long row = row0 + q * 4 + r;
        #pragma unroll
        for (int t = 0; t < 4; ++t) {
            out_ps[row * P + t * 16 + m] = e[t][r] * inv;
        }
    }
}

// ---------------------------------------------------------------------------
extern "C" void kernel_launch(void* const* d_in, const int* in_sizes, int n_in,
                              void* d_out, int out_size, void* d_ws, size_t ws_size,
                              hipStream_t stream) {
    const float* states   = (const float*)d_in[0];   // (4,16,1024,256) fp32
    const float* patterns = (const float*)d_in[1];   // (64,256) fp32
    const float* transfer = (const float*)d_in[2];   // (16,64,64) fp32
    float* out = (float*)d_out;
    _Float16* pnh = (_Float16*)d_ws;                 // 64*256 halves = 32 KB
    _Float16* pnl = pnh + P * D;                     // +32 KB

    k_normalize<<<dim3(P), dim3(64), 0, stream>>>(patterns, pnh, pnl);

    k_small<<<dim3(128), dim3(256), 0, stream>>>((const floatx4*)transfer, out);

    k_routes<<<dim3(4096), dim3(256), 0, stream>>>((floatx4*)(out + OFF_OR));

    k_gemm_mfma<<<dim3(1024), dim3(256), 0, stream>>>(states, pnh, pnl, out + OFF_PS);
}

// Round 7
// 347.236 us; speedup vs baseline: 1.0486x; 1.0486x over previous
//
#include <hip/hip_runtime.h>
#include <math.h>

// Problem shapes
constexpr int B = 4, H = 16, S = 1024, D = 256, P = 64;
constexpr long long N_ROWS = (long long)B * H * S;            // 65536
// Output segment offsets (floats, concatenated in return order)
constexpr long long OFF_RT = 0;                               // routing_scores
constexpr long long SZ_RT  = N_ROWS;                          // 65536
constexpr long long OFF_OR = OFF_RT + SZ_RT;                  // optimal_routes
constexpr long long SZ_OR  = N_ROWS * (long long)S;           // 67108864
constexpr long long OFF_TW = OFF_OR + SZ_OR;                  // transfer_weights
constexpr long long SZ_TW  = 16LL * 64 * 64;                  // 65536
constexpr long long OFF_PS = OFF_TW + SZ_TW;                  // pattern_scores

typedef _Float16 half8   __attribute__((ext_vector_type(8)));
typedef _Float16 half4v  __attribute__((ext_vector_type(4)));
typedef float    floatx4 __attribute__((ext_vector_type(4)));

// ---------------------------------------------------------------------------
// Kernel 1: normalize patterns, fold in 1/TEMPERATURE = 10, split into f16
// hi/lo (a = hi + lo) for split-precision MFMA. Layout [p][k] row-major.
__global__ __launch_bounds__(64) void k_normalize(const float* __restrict__ pat,
                                                  _Float16* __restrict__ pnh,
                                                  _Float16* __restrict__ pnl) {
    int p    = blockIdx.x;
    int lane = threadIdx.x;                 // 0..63, covers 256 floats as floatx4
    const floatx4* src = (const floatx4*)(pat + (long long)p * D);
    floatx4 v = src[lane];
    float ss = v.x * v.x + v.y * v.y + v.z * v.z + v.w * v.w;
    #pragma unroll
    for (int m = 1; m < 64; m <<= 1) ss += __shfl_xor(ss, m, 64);
    float scale = 10.0f / fmaxf(sqrtf(ss), 1e-12f);
    float a[4] = { v.x * scale, v.y * scale, v.z * scale, v.w * scale };
    half4v hh, ll;
    #pragma unroll
    for (int j = 0; j < 4; ++j) {
        _Float16 h = (_Float16)a[j];
        hh[j] = h;
        ll[j] = (_Float16)(a[j] - (float)h);
    }
    *(half4v*)(pnh + (long long)p * D + lane * 4) = hh;
    *(half4v*)(pnl + (long long)p * D + lane * 4) = ll;
}

// ---------------------------------------------------------------------------
// Kernel 2: optimal_routes fill (R2's exact known-good pattern: one plain
// contiguous float4 store per thread — R5 lesson: NT + strided grid-stride
// REGRESSED; plain stores through L2 match the runtime fill's 6.4 TB/s) with
// routing_scores/transfer_weights handled by 128 tail blocks (saves a launch).
__global__ __launch_bounds__(256) void k_routes_small(
        floatx4* __restrict__ routes,
        const floatx4* __restrict__ tw,
        float* __restrict__ out) {
    long long blk = blockIdx.x;
    int t = threadIdx.x;
    if (blk < 65536) {
        long long i = blk * 256 + t;
        int j0 = (int)((i << 2) & (S - 1));          // 1024-periodic column
        float b0 = (float)j0 * (-0.0009765625f);
        floatx4 v;
        v.x = b0;
        v.y = b0 - 0.0009765625f;
        v.z = b0 - 0.001953125f;
        v.w = b0 - 0.0029296875f;
        routes[i] = v;
    } else {
        int i = (int)(blk - 65536) * 256 + t;        // 0..32767
        constexpr int Q = (int)SZ_RT / 4;            // 16384 float4 / segment
        if (i < Q) {
            floatx4 v = { 0.0009765625f, 0.0009765625f,
                          0.0009765625f, 0.0009765625f };
            ((floatx4*)(out + OFF_RT))[i] = v;
        } else {
            ((floatx4*)(out + OFF_TW))[i - Q] = tw[i - Q];
        }
    }
}

// ---------------------------------------------------------------------------
// Kernel 3: sims = states @ pn^T via f16 split-precision MFMA + row softmax.
// R6 restructure for occupancy: wave tile 16 rows x 32 patterns (2 N-tiles,
// acc = 8 VGPRs) -> 8192 waves = 8 waves/SIMD (was 4, grid-limited), to hide
// the ~900-cyc HBM A-load latency. Softmax over 64 cols now spans 2 waves
// (pattern halves) -> 512 B LDS partial max/sum + 2 barriers.
// Block = 256 thr = 4 waves: wave = h*2 + ph; h = row half (16 rows each),
// ph = pattern half (32 cols each). Grid 2048 blocks x 32 rows.
__global__ __launch_bounds__(256, 8) void k_gemm_mfma(
        const float* __restrict__ states,
        const _Float16* __restrict__ pnh,
        const _Float16* __restrict__ pnl,
        float* __restrict__ out_ps) {
    int wave = threadIdx.x >> 6;
    int h    = wave >> 1;                  // row half 0/1
    int ph   = wave & 1;                   // pattern half 0/1
    int lane = threadIdx.x & 63;
    int q    = lane >> 4;                  // quad 0..3
    int m    = lane & 15;
    long long row0 = (long long)blockIdx.x * 32 + h * 16;
    const float* __restrict__ arow = states + (row0 + m) * D + q * 8;

    __shared__ float redmax[2][16][2];
    __shared__ float redsum[2][16][2];

    floatx4 acc[2] = { floatx4{0,0,0,0}, floatx4{0,0,0,0} };

    #pragma unroll 2
    for (int kk = 0; kk < 8; ++kk) {
        float4 a0 = *(const float4*)(arow + kk * 32);
        float4 a1 = *(const float4*)(arow + kk * 32 + 4);
        float av[8] = { a0.x, a0.y, a0.z, a0.w, a1.x, a1.y, a1.z, a1.w };
        half8 ah, al;
        #pragma unroll
        for (int j = 0; j < 8; ++j) {
            _Float16 hh = (_Float16)av[j];
            ah[j] = hh;
            al[j] = (_Float16)(av[j] - (float)hh);
        }
        #pragma unroll
        for (int t = 0; t < 2; ++t) {
            long long boff = (long long)(ph * 32 + t * 16 + m) * D + kk * 32 + q * 8;
            half8 bh = *(const half8*)(pnh + boff);
            half8 bl = *(const half8*)(pnl + boff);
            acc[t] = __builtin_amdgcn_mfma_f32_16x16x32_f16(ah, bh, acc[t], 0, 0, 0);
            acc[t] = __builtin_amdgcn_mfma_f32_16x16x32_f16(al, bh, acc[t], 0, 0, 0);
            acc[t] = __builtin_amdgcn_mfma_f32_16x16x32_f16(ah, bl, acc[t], 0, 0, 0);
        }
    }

    // Partial row-max over this wave's 32 cols (shuffles stay in 16-lane group)
    float pmx[4];
    #pragma unroll
    for (int r = 0; r < 4; ++r) {
        float mx = fmaxf(acc[0][r], acc[1][r]);
        #pragma unroll
        for (int msk = 1; msk < 16; msk <<= 1) mx = fmaxf(mx, __shfl_xor(mx, msk, 64));
        pmx[r] = mx;
        if (m == 0) redmax[h][q * 4 + r][ph] = mx;
    }
    __syncthreads();

    float e[2][4];
    float psum[4];
    #pragma unroll
    for (int r = 0; r < 4; ++r) {
        int rr = q * 4 + r;
        float gmx = fmaxf(redmax[h][rr][0], redmax[h][rr][1]);
        float s = 0.0f;
        #pragma unroll
        for (int t = 0; t < 2; ++t) { e[t][r] = __expf(acc[t][r] - gmx); s += e[t][r]; }
        #pragma unroll
        for (int msk = 1; msk < 16; msk <<= 1) s += __shfl_xor(s, msk, 64);
        psum[r] = s;
        if (m == 0) redsum[h][rr][ph] = s;
    }
    __syncthreads();

    #pragma unroll
    for (int r = 0; r < 4; ++r) {
        int rr = q * 4 + r;
        float inv = 1.0f / (redsum[h][rr][0] + redsum[h][rr][1]);
        long long row = row0 + rr;
        #pragma unroll
        for (int t = 0; t < 2; ++t) {
            out_ps[row * P + ph * 32 + t * 16 + m] = e[t][r] * inv;
        }
    }
    (void)pmx; (void)psum;
}

// ---------------------------------------------------------------------------
extern "C" void kernel_launch(void* const* d_in, const int* in_sizes, int n_in,
                              void* d_out, int out_size, void* d_ws, size_t ws_size,
                              hipStream_t stream) {
    const float* states   = (const float*)d_in[0];   // (4,16,1024,256) fp32
    const float* patterns = (const float*)d_in[1];   // (64,256) fp32
    const float* transfer = (const float*)d_in[2];   // (16,64,64) fp32
    float* out = (float*)d_out;
    _Float16* pnh = (_Float16*)d_ws;                 // 64*256 halves = 32 KB
    _Float16* pnl = pnh + P * D;                     // +32 KB

    k_normalize<<<dim3(P), dim3(64), 0, stream>>>(patterns, pnh, pnl);

    k_routes_small<<<dim3(65536 + 128), dim3(256), 0, stream>>>(
        (floatx4*)(out + OFF_OR), (const floatx4*)transfer, out);

    k_gemm_mfma<<<dim3(2048), dim3(256), 0, stream>>>(states, pnh, pnl, out + OFF_PS);
}

// Round 8
// 330.920 us; speedup vs baseline: 1.1003x; 1.0493x over previous
//
#include <hip/hip_runtime.h>
#include <math.h>

// Problem shapes
constexpr int B = 4, H = 16, S = 1024, D = 256, P = 64;
constexpr long long N_ROWS = (long long)B * H * S;            // 65536
// Output segment offsets (floats, concatenated in return order)
constexpr long long OFF_RT = 0;                               // routing_scores
constexpr long long SZ_RT  = N_ROWS;                          // 65536
constexpr long long OFF_OR = OFF_RT + SZ_RT;                  // optimal_routes
constexpr long long SZ_OR  = N_ROWS * (long long)S;           // 67108864
constexpr long long OFF_TW = OFF_OR + SZ_OR;                  // transfer_weights
constexpr long long SZ_TW  = 16LL * 64 * 64;                  // 65536
constexpr long long OFF_PS = OFF_TW + SZ_TW;                  // pattern_scores

typedef _Float16 half8   __attribute__((ext_vector_type(8)));
typedef _Float16 half4v  __attribute__((ext_vector_type(4)));
typedef float    floatx4 __attribute__((ext_vector_type(4)));

// LDS row stride for B tiles: 256 + 8 halves (16-B pad) keeps ds_read_b128
// 16-B aligned and spreads the 16-lane 512-B-stride fragment reads across
// all 32 banks (8 accesses/bank, balanced = b128 minimum).
constexpr int BSTRIDE = 264;

// ---------------------------------------------------------------------------
// Kernel 1: normalize patterns, fold in 1/TEMPERATURE = 10, split into f16
// hi/lo (a = hi + lo) for split-precision MFMA. Layout [p][k] row-major.
__global__ __launch_bounds__(64) void k_normalize(const float* __restrict__ pat,
                                                  _Float16* __restrict__ pnh,
                                                  _Float16* __restrict__ pnl) {
    int p    = blockIdx.x;
    int lane = threadIdx.x;                 // 0..63, covers 256 floats as floatx4
    const floatx4* src = (const floatx4*)(pat + (long long)p * D);
    floatx4 v = src[lane];
    float ss = v.x * v.x + v.y * v.y + v.z * v.z + v.w * v.w;
    #pragma unroll
    for (int m = 1; m < 64; m <<= 1) ss += __shfl_xor(ss, m, 64);
    float scale = 10.0f / fmaxf(sqrtf(ss), 1e-12f);
    float a[4] = { v.x * scale, v.y * scale, v.z * scale, v.w * scale };
    half4v hh, ll;
    #pragma unroll
    for (int j = 0; j < 4; ++j) {
        _Float16 h = (_Float16)a[j];
        hh[j] = h;
        ll[j] = (_Float16)(a[j] - (float)h);
    }
    *(half4v*)(pnh + (long long)p * D + lane * 4) = hh;
    *(half4v*)(pnl + (long long)p * D + lane * 4) = ll;
}

// ---------------------------------------------------------------------------
// Kernel 2: optimal_routes fill (R2's known-good plain contiguous float4
// store — R5: NT + strided grid-stride regressed) with routing_scores /
// transfer_weights in 128 tail blocks (saves a launch).
__global__ __launch_bounds__(256) void k_routes_small(
        floatx4* __restrict__ routes,
        const floatx4* __restrict__ tw,
        float* __restrict__ out) {
    long long blk = blockIdx.x;
    int t = threadIdx.x;
    if (blk < 65536) {
        long long i = blk * 256 + t;
        int j0 = (int)((i << 2) & (S - 1));          // 1024-periodic column
        float b0 = (float)j0 * (-0.0009765625f);
        floatx4 v;
        v.x = b0;
        v.y = b0 - 0.0009765625f;
        v.z = b0 - 0.001953125f;
        v.w = b0 - 0.0029296875f;
        routes[i] = v;
    } else {
        int i = (int)(blk - 65536) * 256 + t;        // 0..32767
        constexpr int Q = (int)SZ_RT / 4;            // 16384 float4 / segment
        if (i < Q) {
            floatx4 v = { 0.0009765625f, 0.0009765625f,
                          0.0009765625f, 0.0009765625f };
            ((floatx4*)(out + OFF_RT))[i] = v;
        } else {
            ((floatx4*)(out + OFF_TW))[i - Q] = tw[i - Q];
        }
    }
}

// ---------------------------------------------------------------------------
// Kernel 3 (gemm v3): sims = states @ pn^T via f16 split-precision MFMA +
// row softmax. R7 change: stage B (pnh+pnl, 64 KB) into LDS ONCE per block
// with fully-coalesced 1-KB wave loads, then read fragments via balanced
// ds_read_b128 — eliminates the per-thread global B re-reads (16-line
// gathers thrashing the 32 KB L1, ~256 MB of L2 transactions). A-loads stay
// direct from global (read-once, line-covered within each K-step).
// Block = 256 thr = 4 waves; tile 64 rows x 64 patterns; LDS 66 KB -> 2 blk/CU.
__global__ __launch_bounds__(256) void k_gemm_mfma(
        const float* __restrict__ states,
        const _Float16* __restrict__ pnh,
        const _Float16* __restrict__ pnl,
        float* __restrict__ out_ps) {
    __shared__ _Float16 smem[2 * P * BSTRIDE];       // Bh then Bl
    _Float16* smH = smem;
    _Float16* smL = smem + P * BSTRIDE;

    int tid  = threadIdx.x;
    // --- Phase 0: stage B into LDS (coalesced) -----------------------------
    {
        const half8* gh = (const half8*)pnh;         // 2048 x 16 B chunks
        const half8* gl = (const half8*)pnl;
        #pragma unroll
        for (int it = 0; it < 8; ++it) {
            int idx = it * 256 + tid;
            int row = idx >> 5;                      // pattern row
            int c8  = idx & 31;                      // 8-half chunk in row
            *(half8*)&smH[row * BSTRIDE + c8 * 8] = gh[idx];
            *(half8*)&smL[row * BSTRIDE + c8 * 8] = gl[idx];
        }
    }
    __syncthreads();

    int wave = tid >> 6;
    int lane = tid & 63;
    int q    = lane >> 4;                  // quad 0..3
    int m    = lane & 15;
    long long row0 = (long long)blockIdx.x * 64 + wave * 16;
    const float* __restrict__ arow = states + (row0 + m) * D + q * 8;

    floatx4 acc[4] = {floatx4{0,0,0,0}, floatx4{0,0,0,0},
                      floatx4{0,0,0,0}, floatx4{0,0,0,0}};

    float4 n0 = *(const float4*)(arow);
    float4 n1 = *(const float4*)(arow + 4);
    #pragma unroll
    for (int kk = 0; kk < 8; ++kk) {
        float4 a0 = n0, a1 = n1;
        if (kk < 7) {                                 // prefetch next A chunk
            n0 = *(const float4*)(arow + (kk + 1) * 32);
            n1 = *(const float4*)(arow + (kk + 1) * 32 + 4);
        }
        float av[8] = { a0.x, a0.y, a0.z, a0.w, a1.x, a1.y, a1.z, a1.w };
        half8 ah, al;
        #pragma unroll
        for (int j = 0; j < 8; ++j) {
            _Float16 h = (_Float16)av[j];
            ah[j] = h;
            al[j] = (_Float16)(av[j] - (float)h);
        }
        #pragma unroll
        for (int t = 0; t < 4; ++t) {
            int boff = (t * 16 + m) * BSTRIDE + kk * 32 + q * 8;
            half8 bh = *(const half8*)&smH[boff];
            half8 bl = *(const half8*)&smL[boff];
            acc[t] = __builtin_amdgcn_mfma_f32_16x16x32_f16(ah, bh, acc[t], 0, 0, 0);
            acc[t] = __builtin_amdgcn_mfma_f32_16x16x32_f16(al, bh, acc[t], 0, 0, 0);
            acc[t] = __builtin_amdgcn_mfma_f32_16x16x32_f16(ah, bl, acc[t], 0, 0, 0);
        }
    }

    // Row softmax: row = q*4 + r lives in the 16 lanes sharing q (shuffle
    // masks 1..8 stay inside the group); each lane holds 4 cols (one per tile).
    float e[4][4];
    #pragma unroll
    for (int r = 0; r < 4; ++r) {
        float mx = fmaxf(fmaxf(acc[0][r], acc[1][r]), fmaxf(acc[2][r], acc[3][r]));
        #pragma unroll
        for (int msk = 1; msk < 16; msk <<= 1) mx = fmaxf(mx, __shfl_xor(mx, msk, 64));
        float s = 0.0f;
        #pragma unroll
        for (int t = 0; t < 4; ++t) { e[t][r] = __expf(acc[t][r] - mx); s += e[t][r]; }
        #pragma unroll
        for (int msk = 1; msk < 16; msk <<= 1) s += __shfl_xor(s, msk, 64);
        float inv = 1.0f / s;
        long long row = row0 + q * 4 + r;
        #pragma unroll
        for (int t = 0; t < 4; ++t) {
            out_ps[row * P + t * 16 + m] = e[t][r] * inv;
        }
    }
}

// ---------------------------------------------------------------------------
extern "C" void kernel_launch(void* const* d_in, const int* in_sizes, int n_in,
                              void* d_out, int out_size, void* d_ws, size_t ws_size,
                              hipStream_t stream) {
    const float* states   = (const float*)d_in[0];   // (4,16,1024,256) fp32
    const float* patterns = (const float*)d_in[1];   // (64,256) fp32
    const float* transfer = (const float*)d_in[2];   // (16,64,64) fp32
    float* out = (float*)d_out;
    _Float16* pnh = (_Float16*)d_ws;                 // 64*256 halves = 32 KB
    _Float16* pnl = pnh + P * D;                     // +32 KB

    k_normalize<<<dim3(P), dim3(64), 0, stream>>>(patterns, pnh, pnl);

    k_routes_small<<<dim3(65536 + 128), dim3(256), 0, stream>>>(
        (floatx4*)(out + OFF_OR), (const floatx4*)transfer, out);

    k_gemm_mfma<<<dim3(1024), dim3(256), 0, stream>>>(states, pnh, pnl, out + OFF_PS);
}

// Round 9
// 324.598 us; speedup vs baseline: 1.1218x; 1.0195x over previous
//
#include <hip/hip_runtime.h>
#include <math.h>

// Problem shapes
constexpr int B = 4, H = 16, S = 1024, D = 256, P = 64;
constexpr long long N_ROWS = (long long)B * H * S;            // 65536
// Output segment offsets (floats, concatenated in return order)
constexpr long long OFF_RT = 0;                               // routing_scores
constexpr long long SZ_RT  = N_ROWS;                          // 65536
constexpr long long OFF_OR = OFF_RT + SZ_RT;                  // optimal_routes
constexpr long long SZ_OR  = N_ROWS * (long long)S;           // 67108864
constexpr long long OFF_TW = OFF_OR + SZ_OR;                  // transfer_weights
constexpr long long SZ_TW  = 16LL * 64 * 64;                  // 65536
constexpr long long OFF_PS = OFF_TW + SZ_TW;                  // pattern_scores

typedef _Float16 half8   __attribute__((ext_vector_type(8)));
typedef _Float16 half4v  __attribute__((ext_vector_type(4)));
typedef float    floatx4 __attribute__((ext_vector_type(4)));

// LDS row stride for B tiles: 256 + 8 halves (16-B pad) keeps ds_read_b128
// 16-B aligned and balances the 16-lane fragment reads across banks.
constexpr int BSTRIDE = 264;

// ---------------------------------------------------------------------------
// Kernel 1 (fused fill + prep): 65536 route blocks, 128 small-segment blocks,
// 16 normalize blocks.
//   routes: R2's known-good plain contiguous float4 store (R5: NT+strided
//   regressed). normalize: fold 1/T=10, split into f16 hi/lo for
//   split-precision MFMA, layout [p][k].
__global__ __launch_bounds__(256) void k_fill_prep(
        floatx4* __restrict__ routes,
        const floatx4* __restrict__ tw,
        float* __restrict__ out,
        const float* __restrict__ pat,
        _Float16* __restrict__ pnh,
        _Float16* __restrict__ pnl) {
    long long blk = blockIdx.x;
    int t = threadIdx.x;
    if (blk < 65536) {
        long long i = blk * 256 + t;
        int j0 = (int)((i << 2) & (S - 1));          // 1024-periodic column
        float b0 = (float)j0 * (-0.0009765625f);
        floatx4 v;
        v.x = b0;
        v.y = b0 - 0.0009765625f;
        v.z = b0 - 0.001953125f;
        v.w = b0 - 0.0029296875f;
        routes[i] = v;
    } else if (blk < 65536 + 128) {
        int i = (int)(blk - 65536) * 256 + t;        // 0..32767
        constexpr int Q = (int)SZ_RT / 4;            // 16384 float4 / segment
        if (i < Q) {
            floatx4 v = { 0.0009765625f, 0.0009765625f,
                          0.0009765625f, 0.0009765625f };
            ((floatx4*)(out + OFF_RT))[i] = v;
        } else {
            ((floatx4*)(out + OFF_TW))[i - Q] = tw[i - Q];
        }
    } else {
        // normalize: 16 blocks x 4 waves, one pattern per wave
        int p    = (int)(blk - 65536 - 128) * 4 + (t >> 6);
        int lane = t & 63;
        const floatx4* src = (const floatx4*)(pat + (long long)p * D);
        floatx4 v = src[lane];
        float ss = v.x * v.x + v.y * v.y + v.z * v.z + v.w * v.w;
        #pragma unroll
        for (int m = 1; m < 64; m <<= 1) ss += __shfl_xor(ss, m, 64);
        float scale = 10.0f / fmaxf(sqrtf(ss), 1e-12f);
        float a[4] = { v.x * scale, v.y * scale, v.z * scale, v.w * scale };
        half4v hh, ll;
        #pragma unroll
        for (int j = 0; j < 4; ++j) {
            _Float16 h = (_Float16)a[j];
            hh[j] = h;
            ll[j] = (_Float16)(a[j] - (float)h);
        }
        *(half4v*)(pnh + (long long)p * D + lane * 4) = hh;
        *(half4v*)(pnl + (long long)p * D + lane * 4) = ll;
    }
}

// ---------------------------------------------------------------------------
// Kernel 2 (gemm v4): sims = states @ pn^T via f16 split-precision MFMA +
// row softmax. R8 change: wave tile 32 rows x 64 patterns (128-row blocks,
// 512 blocks) — each LDS B-fragment pair now feeds 6 MFMAs instead of 3,
// halving ds_read cycles per FLOP (R7 showed the K-loop is LDS/VMEM-issue
// heavy, not latency-bound per R6). B staged in LDS once per block
// (coalesced, R7 win). acc = 2 row sets x 4 N-tiles x 4 = 32 VGPRs.
__global__ __launch_bounds__(256) void k_gemm_mfma(
        const float* __restrict__ states,
        const _Float16* __restrict__ pnh,
        const _Float16* __restrict__ pnl,
        float* __restrict__ out_ps) {
    __shared__ _Float16 smem[2 * P * BSTRIDE];       // Bh then Bl
    _Float16* smH = smem;
    _Float16* smL = smem + P * BSTRIDE;

    int tid  = threadIdx.x;
    // --- Phase 0: stage B into LDS (coalesced) -----------------------------
    {
        const half8* gh = (const half8*)pnh;         // 2048 x 16 B chunks
        const half8* gl = (const half8*)pnl;
        #pragma unroll
        for (int it = 0; it < 8; ++it) {
            int idx = it * 256 + tid;
            int row = idx >> 5;                      // pattern row
            int c8  = idx & 31;                      // 8-half chunk in row
            *(half8*)&smH[row * BSTRIDE + c8 * 8] = gh[idx];
            *(half8*)&smL[row * BSTRIDE + c8 * 8] = gl[idx];
        }
    }
    __syncthreads();

    int wave = tid >> 6;
    int lane = tid & 63;
    int q    = lane >> 4;                  // quad 0..3
    int m    = lane & 15;
    long long row0 = (long long)blockIdx.x * 128 + wave * 32;
    const float* __restrict__ arow0 = states + (row0 + m) * D + q * 8;
    const float* __restrict__ arow1 = arow0 + 16 * D;

    floatx4 acc0[4] = {floatx4{0,0,0,0}, floatx4{0,0,0,0},
                       floatx4{0,0,0,0}, floatx4{0,0,0,0}};
    floatx4 acc1[4] = {floatx4{0,0,0,0}, floatx4{0,0,0,0},
                       floatx4{0,0,0,0}, floatx4{0,0,0,0}};

    float4 n0 = *(const float4*)(arow0);
    float4 n1 = *(const float4*)(arow0 + 4);
    float4 n2 = *(const float4*)(arow1);
    float4 n3 = *(const float4*)(arow1 + 4);
    #pragma unroll
    for (int kk = 0; kk < 8; ++kk) {
        float av0[8] = { n0.x, n0.y, n0.z, n0.w, n1.x, n1.y, n1.z, n1.w };
        float av1[8] = { n2.x, n2.y, n2.z, n2.w, n3.x, n3.y, n3.z, n3.w };
        if (kk < 7) {                                 // prefetch next A chunks
            n0 = *(const float4*)(arow0 + (kk + 1) * 32);
            n1 = *(const float4*)(arow0 + (kk + 1) * 32 + 4);
            n2 = *(const float4*)(arow1 + (kk + 1) * 32);
            n3 = *(const float4*)(arow1 + (kk + 1) * 32 + 4);
        }
        half8 ah0, al0, ah1, al1;
        #pragma unroll
        for (int j = 0; j < 8; ++j) {
            _Float16 h0 = (_Float16)av0[j];
            ah0[j] = h0;
            al0[j] = (_Float16)(av0[j] - (float)h0);
            _Float16 h1 = (_Float16)av1[j];
            ah1[j] = h1;
            al1[j] = (_Float16)(av1[j] - (float)h1);
        }
        #pragma unroll
        for (int t = 0; t < 4; ++t) {
            int boff = (t * 16 + m) * BSTRIDE + kk * 32 + q * 8;
            half8 bh = *(const half8*)&smH[boff];
            half8 bl = *(const half8*)&smL[boff];
            acc0[t] = __builtin_amdgcn_mfma_f32_16x16x32_f16(ah0, bh, acc0[t], 0, 0, 0);
            acc0[t] = __builtin_amdgcn_mfma_f32_16x16x32_f16(al0, bh, acc0[t], 0, 0, 0);
            acc0[t] = __builtin_amdgcn_mfma_f32_16x16x32_f16(ah0, bl, acc0[t], 0, 0, 0);
            acc1[t] = __builtin_amdgcn_mfma_f32_16x16x32_f16(ah1, bh, acc1[t], 0, 0, 0);
            acc1[t] = __builtin_amdgcn_mfma_f32_16x16x32_f16(al1, bh, acc1[t], 0, 0, 0);
            acc1[t] = __builtin_amdgcn_mfma_f32_16x16x32_f16(ah1, bl, acc1[t], 0, 0, 0);
        }
    }

    // Row softmax per row set: row = q*4 + r lives in the 16 lanes sharing q
    // (shuffle masks 1..8 stay in-group); lane holds 4 cols (one per N-tile).
    #pragma unroll
    for (int set = 0; set < 2; ++set) {
        floatx4* acc = set ? acc1 : acc0;
        long long rbase = row0 + set * 16;
        #pragma unroll
        for (int r = 0; r < 4; ++r) {
            float mx = fmaxf(fmaxf(acc[0][r], acc[1][r]),
                             fmaxf(acc[2][r], acc[3][r]));
            #pragma unroll
            for (int msk = 1; msk < 16; msk <<= 1)
                mx = fmaxf(mx, __shfl_xor(mx, msk, 64));
            float e[4];
            float s = 0.0f;
            #pragma unroll
            for (int t = 0; t < 4; ++t) { e[t] = __expf(acc[t][r] - mx); s += e[t]; }
            #pragma unroll
            for (int msk = 1; msk < 16; msk <<= 1) s += __shfl_xor(s, msk, 64);
            float inv = 1.0f / s;
            long long row = rbase + q * 4 + r;
            #pragma unroll
            for (int t = 0; t < 4; ++t) {
                out_ps[row * P + t * 16 + m] = e[t] * inv;
            }
        }
    }
}

// ---------------------------------------------------------------------------
extern "C" void kernel_launch(void* const* d_in, const int* in_sizes, int n_in,
                              void* d_out, int out_size, void* d_ws, size_t ws_size,
                              hipStream_t stream) {
    const float* states   = (const float*)d_in[0];   // (4,16,1024,256) fp32
    const float* patterns = (const float*)d_in[1];   // (64,256) fp32
    const float* transfer = (const float*)d_in[2];   // (16,64,64) fp32
    float* out = (float*)d_out;
    _Float16* pnh = (_Float16*)d_ws;                 // 64*256 halves = 32 KB
    _Float16* pnl = pnh + P * D;                     // +32 KB

    k_fill_prep<<<dim3(65536 + 128 + 16), dim3(256), 0, stream>>>(
        (floatx4*)(out + OFF_OR), (const floatx4*)transfer, out,
        patterns, pnh, pnl);

    k_gemm_mfma<<<dim3(512), dim3(256), 0, stream>>>(states, pnh, pnl, out + OFF_PS);
}